// Round 7
// baseline (199.888 us; speedup 1.0000x reference)
//
#include <hip/hip_runtime.h>

// Problem constants (frozen by the reference)
#define NN 16
#define CC 64
#define HH 128
#define WW 128

#define LDS_STRIDE 72    // bf16 elems per xsT row (144 B; dword stride 36)
#define T3B_STRIDE 132   // bf16 elems per t3b row (264 B, 8B-aligned rows)

typedef __attribute__((ext_vector_type(8))) short short8;   // bf16x8 (4 VGPRs)
typedef __attribute__((ext_vector_type(4))) float floatx4;  // MFMA C/D

__device__ __forceinline__ short f2bf(float f) {
    union { float f; unsigned u; } v; v.f = f;
    unsigned r = v.u + 0x7fffu + ((v.u >> 16) & 1u);
    return (short)(r >> 16);
}
__device__ __forceinline__ unsigned pack2bf(float lo, float hi) {
    union { float f; unsigned u; } a, b; a.f = lo; b.f = hi;
    unsigned ra = a.u + 0x7fffu + ((a.u >> 16) & 1u);
    unsigned rb = b.u + 0x7fffu + ((b.u >> 16) & 1u);
    return (ra >> 16) | (rb & 0xffff0000u);
}
__device__ __forceinline__ float bf2f(unsigned short u) {
    union { unsigned u; float f; } v; v.u = ((unsigned)u) << 16;
    return v.f;
}

// ---------------------------------------------------------------------------
// Kernel 0: w3 (co, ci, 1, 5) fp32 -> Abf[co][kk] bf16, kk = tap*64 + ci.
// ---------------------------------------------------------------------------
__global__ __launch_bounds__(256) void prep_w(const float* __restrict__ w3,
                                              short* __restrict__ Abf) {
    int idx = blockIdx.x * 256 + threadIdx.x;
    if (idx < CC * CC * 5) {
        int tap = idx % 5;
        int ci  = (idx / 5) % CC;
        int co  = idx / (5 * CC);
        Abf[co * 320 + tap * 64 + ci] = f2bf(w3[idx]);
    }
}

// ---------------------------------------------------------------------------
// Fused kernel, 512 threads per block, one block per (n,h) row.
// Register budget is the whole design: acc[4] = 16 AGPR (each of 8 waves owns
// co-tile (wave&3) x 4 w-tiles (wave>>2)), __launch_bounds__(512,8) caps the
// unified file at 64 regs -> 8 waves/EU, 4 blocks/CU, 32 waves/CU (2x R6).
// LDS (no aliasing): xsT 19008 + t3b 16896 + ws7 3072 = 38976 B -> 4 blk/CU.
// Phase 4 is register-light: clamped row pointers + loop-invariant masks
// (no zero page), w7 from LDS, simple body (TLP hides latency at 32 waves).
// ---------------------------------------------------------------------------
__global__ __launch_bounds__(512, 8) void fused(const float* __restrict__ x,
                                                const short* __restrict__ Abf,
                                                const float* __restrict__ w7,
                                                float* __restrict__ out) {
    __shared__ __align__(16) char smem[132 * LDS_STRIDE * 2 + CC * T3B_STRIDE * 2 + 768 * 4];
    short*    xsT = (short*)smem;                         // [132][72] bf16
    unsigned* xsW = (unsigned*)smem;                      // dword view, stride 36
    short*    t3b = (short*)(smem + 132 * LDS_STRIDE * 2);                 // [64][132] bf16
    float*    ws7 = (float*)(smem + 132 * LDS_STRIDE * 2 + CC * T3B_STRIDE * 2); // [64][12] f32

    const int bid = blockIdx.x;
    const int nh  = ((bid & 7) << 8) | (bid >> 3);   // XCD-contiguous h
    const int n   = nh >> 7;
    const int h   = nh & (HH - 1);
    const int tid = threadIdx.x;

    // ---- Phase 1: stage x row h transposed bf16 (packed ci-pairs) + w7 ----
    const float* xbase = x + (((size_t)n * CC) * HH + h) * WW;
    {
        const int cp  = tid & 31;       // ci pair: rows 2cp, 2cp+1
        const int wqg = tid >> 5;       // 0..15 -> w-strip of 8 (2 float4)
        const float* r0 = xbase + (size_t)(2 * cp) * (HH * WW);
        const float* r1 = r0 + HH * WW;
        #pragma unroll
        for (int q = 0; q < 2; ++q) {
            int wq = wqg * 2 + q;
            float4 a = *(const float4*)(r0 + wq * 4);
            float4 b = *(const float4*)(r1 + wq * 4);
            int wp = wq * 4 + 2;
            xsW[(wp + 0) * 36 + cp] = pack2bf(a.x, b.x);
            xsW[(wp + 1) * 36 + cp] = pack2bf(a.y, b.y);
            xsW[(wp + 2) * 36 + cp] = pack2bf(a.z, b.z);
            xsW[(wp + 3) * 36 + cp] = pack2bf(a.w, b.w);
        }
        if (tid < 128) {    // zero pad rows wp in {0,1,130,131}
            int wpi = tid >> 5;
            int wpz = (wpi < 2) ? wpi : 128 + wpi;
            xsW[wpz * 36 + (tid & 31)] = 0u;
        }
        // stage w7 into LDS, stride 12 (16B-aligned rows)
        for (int i = tid; i < CC * 9; i += 512) {
            int c = i / 9, j = i - c * 9;
            ws7[c * 12 + j] = w7[i];
        }
    }
    __syncthreads();

    // ---- Phase 2: MFMA (wave -> co-tile (wv&3), w-tiles 4*(wv>>2)..+3) ----
    const int wv   = tid >> 6;
    const int lane = tid & 63;
    const int lm   = lane & 15;
    const int g    = lane >> 4;
    const int ct   = wv & 3;
    const int ntb  = (wv >> 2) * 4;

    floatx4 acc[4];
    #pragma unroll
    for (int k = 0; k < 4; ++k) acc[k] = (floatx4){0.f, 0.f, 0.f, 0.f};

    const short* arow = Abf + (ct * 16 + lm) * 320;

    for (int ks = 0; ks < 10; ++ks) {
        const int kbase = ks * 32 + g * 8;
        const int tap   = kbase >> 6;
        const int cib   = kbase & 63;

        short8 a = *(const short8*)(arow + kbase);
        #pragma unroll
        for (int k = 0; k < 4; ++k) {
            int wp = (ntb + k) * 16 + lm + tap;
            short8 b = *(const short8*)&xsT[wp * LDS_STRIDE + cib];
            acc[k] = __builtin_amdgcn_mfma_f32_16x16x32_bf16(a, b, acc[k], 0, 0, 0);
        }
    }

    // ---- Phase 3: epilogue to LDS (bf16) ----
    #pragma unroll
    for (int k = 0; k < 4; ++k) {
        #pragma unroll
        for (int r = 0; r < 4; ++r) {
            int co = ct * 16 + g * 4 + r;
            t3b[co * T3B_STRIDE + (ntb + k) * 16 + lm] = f2bf(acc[k][r]);
        }
    }
    __syncthreads();

    // ---- Phase 4: combine, 4 outputs/thread, 4 iterations over c ----
    const int chi = tid >> 5;            // c = it*16 + chi
    const int w0  = (tid & 31) * 4;
    const bool isw  = (w0 == 0);
    const bool cok0 = (w0 > 0);
    const bool cok2 = (w0 < 124);
    const int  src  = lane | 31;         // shfl source for wrap values
    const int coff0 = cok0 ? (w0 - 4) : 0;
    const int coff2 = cok2 ? (w0 + 4) : 124;

    const float* rp[3];
    bool hok[3];
    #pragma unroll
    for (int r = 0; r < 3; ++r) {
        int hh = h + r - 1;
        hok[r] = (unsigned)hh < HH;
        int hcl = hh < 0 ? 0 : (hh > HH - 1 ? HH - 1 : hh);
        rp[r] = x + (((size_t)(n * CC + chi)) * HH + hcl) * WW;
    }
    float* outp = out + ((((size_t)(n * CC + chi)) * HH + h) * WW) + w0;
    int t3o = chi * T3B_STRIDE + w0;
    const float* wrow = ws7 + chi * 12;

    #pragma unroll
    for (int it = 0; it < 4; ++it) {
        // window win[r][idx] = col w0-4+idx of row h+r-1 (0 where OOB)
        float win[3][12];
        #pragma unroll
        for (int r = 0; r < 3; ++r) {
            float4 v0 = *(const float4*)(rp[r] + coff0);
            float4 v1 = *(const float4*)(rp[r] + w0);
            float4 v2 = *(const float4*)(rp[r] + coff2);
            bool m0 = hok[r] && cok0, m1 = hok[r], m2 = hok[r] && cok2;
            win[r][0]  = m0 ? v0.x : 0.f; win[r][1]  = m0 ? v0.y : 0.f;
            win[r][2]  = m0 ? v0.z : 0.f; win[r][3]  = m0 ? v0.w : 0.f;
            win[r][4]  = m1 ? v1.x : 0.f; win[r][5]  = m1 ? v1.y : 0.f;
            win[r][6]  = m1 ? v1.z : 0.f; win[r][7]  = m1 ? v1.w : 0.f;
            win[r][8]  = m2 ? v2.x : 0.f; win[r][9]  = m2 ? v2.y : 0.f;
            win[r][10] = m2 ? v2.z : 0.f; win[r][11] = m2 ? v2.w : 0.f;
        }
        // wrap (w==0 roll): cols 125,127 live in lane tid|31's middle quad
        float wrap0[3], wrap1[3];
        #pragma unroll
        for (int r = 0; r < 3; ++r) {
            wrap0[r] = __shfl(win[r][5], src);
            wrap1[r] = __shfl(win[r][7], src);
        }

        float4 wca = *(const float4*)(wrow);
        float4 wcb = *(const float4*)(wrow + 4);
        float  wcl = wrow[8];
        float wc[9] = {wca.x, wca.y, wca.z, wca.w, wcb.x, wcb.y, wcb.z, wcb.w, wcl};

        ushort4 tv = *(const ushort4*)&t3b[t3o];
        float t3v[4] = {bf2f(tv.x), bf2f(tv.y), bf2f(tv.z), bf2f(tv.w)};

        float res[4];
        #pragma unroll
        for (int e = 0; e < 4; ++e) {
            float a = 0.f;
            #pragma unroll
            for (int j = 0; j < 3; ++j) {
                #pragma unroll
                for (int i = 0; i < 3; ++i) {
                    float lhs = win[1][e + 2 * i + 2];        // col w+2(i-1)
                    float rhs = win[i][e + 2 * j + 1];        // col w+2j-3
                    if (e == 0)
                        rhs = isw ? ((j == 0) ? wrap0[i]
                                   : (j == 1) ? wrap1[i] : 0.f)
                                  : rhs;
                    a = fmaf(wc[j * 3 + i], fmaxf(lhs, rhs), a);
                }
            }
            res[e] = a;
        }
        float4 o;
        o.x = res[0] * t3v[0]; o.y = res[1] * t3v[1];
        o.z = res[2] * t3v[2]; o.w = res[3] * t3v[3];
        *(float4*)outp = o;

        // advance to c += 16
        #pragma unroll
        for (int r = 0; r < 3; ++r) rp[r] += (size_t)16 * HH * WW;
        outp += (size_t)16 * HH * WW;
        t3o  += 16 * T3B_STRIDE;
        wrow += 16 * 12;
    }
}

extern "C" void kernel_launch(void* const* d_in, const int* in_sizes, int n_in,
                              void* d_out, int out_size, void* d_ws, size_t ws_size,
                              hipStream_t stream) {
    const float* x  = (const float*)d_in[0];
    const float* w3 = (const float*)d_in[1];
    const float* w7 = (const float*)d_in[2];
    float* out = (float*)d_out;

    short* Abf = (short*)d_ws;   // 40960 B bf16 weights

    prep_w<<<(CC * CC * 5 + 255) / 256, 256, 0, stream>>>(w3, Abf);
    fused<<<NN * HH, 512, 0, stream>>>(x, Abf, w7, out);
}